// Round 7
// baseline (732.941 us; speedup 1.0000x reference)
//
#include <hip/hip_runtime.h>

// ---------------- dtype helpers ----------------
__device__ __forceinline__ float b2f(unsigned short u) {
  return __uint_as_float(((unsigned)u) << 16);
}
__device__ __forceinline__ unsigned short f2b(float f) {
  unsigned u = __float_as_uint(f);
  return (unsigned short)((u + 0x7FFFu + ((u >> 16) & 1u)) >> 16);
}
// load element i of a tensor that is bf16 (isb=1) or fp32 (isb=0)
__device__ __forceinline__ float gload(const void* p, int i, int isb) {
  return isb ? b2f(((const unsigned short*)p)[i]) : ((const float*)p)[i];
}
// monotone bijection float -> uint32 (order-preserving incl. negatives)
__device__ __forceinline__ unsigned tokey(float f) {
  unsigned u = __float_as_uint(f);
  return u ^ (unsigned)(((int)u >> 31) | 0x80000000u);
}

// ---------------- dtype detector (dataset proven fp32; kept for safety) ----------------
__global__ void k_detect(const void* x, int* flag) {
  int tid = threadIdx.x;  // 1 wave
  unsigned short u = ((const unsigned short*)x)[2 * tid];
  int e = (u >> 7) & 0xFF;
  bool sane = (e >= 100 && e <= 140);
  unsigned long long m = __ballot(sane);
  if (tid == 0) *flag = (__popcll(m) >= 40) ? 1 : 0;
}

// ---------------- k_prep: WtF[i][u] = fc1_w[u][i] * (mask<0.5), f32 transposed ----------------
__global__ __launch_bounds__(256) void k_prep(const void* __restrict__ fc1w,
                                              const void* __restrict__ mraw,
                                              float* __restrict__ WtF,
                                              const int* __restrict__ flag) {
  __shared__ float tile[64][65];
  const int isb = *flag;
  const int i0 = blockIdx.x * 64;  // K index (9216)
  const int u0 = blockIdx.y * 64;  // unit index (1024)
  const int tx = threadIdx.x & 63, ty = threadIdx.x >> 6;
  for (int uu = ty; uu < 64; uu += 4) {
    int gi = (u0 + uu) * 9216 + i0 + tx;
    float wv = gload(fc1w, gi, isb);
    float mv = gload(mraw, gi, isb);
    tile[uu][tx] = (mv < 0.5f) ? wv : 0.0f;
  }
  __syncthreads();
  for (int ii = ty; ii < 64; ii += 4)
    WtF[(i0 + ii) * 1024 + u0 + tx] = tile[tx][ii];
}

// ---------------- k_conv: r3-proven form (204us, VGPR 80, zero spill) ----------------
// v5/v6 post-mortem: both attempts to shrink LDS for occupancy (candidate
// bitmask; pair-exchange) forced arrays live across the conv loop -> scratch
// spill (WRITE_SIZE 160MB / 85MB), net regressions. The conv kernel is
// register-pressure-locked at this structure; r3's version is the local
// optimum. Restored VERBATIM.
__global__ __launch_bounds__(256) void k_conv(const void* __restrict__ x,
                                              const void* __restrict__ c1w_g,
                                              const void* __restrict__ c1b_g,
                                              const void* __restrict__ duty_g,
                                              int2* __restrict__ wpair,
                                              int* __restrict__ wcnt,
                                              const int* __restrict__ flag) {
  __shared__ __align__(16) float img[784];
  __shared__ float cw[1600];
  __shared__ float cb[64], bcs[64];
  __shared__ __align__(16) float pooled[9216];
  __shared__ unsigned hist4[4][256];
  __shared__ unsigned wtot[4];
  __shared__ unsigned selb, selk;
  const int tid = threadIdx.x;
  const int b = blockIdx.x;
  const int isb = *flag;
  const int lane = tid & 63;
  const int wv_id = tid >> 6;

  for (int i = tid; i < 784; i += 256) img[i] = gload(x, b * 784 + i, isb);
  for (int i = tid; i < 1600; i += 256) cw[i] = gload(c1w_g, i, isb);
  if (tid < 64) {
    cb[tid] = gload(c1b_g, tid, isb);
    float arg = (float)(400.0 / 9216.0) - gload(duty_g, tid, isb);
    bcs[tid] = (float)exp((double)arg);
  }
  __syncthreads();

  // mapping: c = tid>>2 (64), half = tid&1 (2), pg = (tid>>1)&1 (2) -> ph0 = pg*6
  {
    const int c = tid >> 2;
    const int half = tid & 1;
    const int ph0 = ((tid >> 1) & 1) * 6;
    float w[25];
#pragma unroll
    for (int i = 0; i < 25; ++i) w[i] = cw[c * 25 + i];
    const float bias = cb[c];
    float R[6][16];
#pragma unroll
    for (int r = 0; r < 6; ++r) {
      int ir = 2 * ph0 + r;
#pragma unroll
      for (int q = 0; q < 4; ++q)
        ((float4*)&R[r][0])[q] = ((const float4*)img)[ir * 7 + half * 3 + q];
    }
#pragma unroll
    for (int i = 0; i < 6; ++i) {
      const int ph = ph0 + i;
      float a0[12], a1[12];
#pragma unroll
      for (int j = 0; j < 12; ++j) { a0[j] = 0.f; a1[j] = 0.f; }
      // single sequential fmaf chain per conv cell, k = kw*5 + kh order
      // (kh fastest -- Eigen patch linearization) => bit-exact vs reference
#pragma unroll
      for (int kj = 0; kj < 5; ++kj) {       // kw OUTER
#pragma unroll
        for (int kr = 0; kr < 5; ++kr) {     // kh INNER (fastest)
          float wk = w[kr * 5 + kj];
          const float* r0 = &R[(2 * i + kr) % 6][0];
          const float* r1 = &R[(2 * i + kr + 1) % 6][0];
#pragma unroll
          for (int j = 0; j < 12; ++j) {
            a0[j] = fmaf(r0[j + kj], wk, a0[j]);
            a1[j] = fmaf(r1[j + kj], wk, a1[j]);
          }
        }
      }
      int obase = c * 144 + ph * 12 + half * 6;
#pragma unroll
      for (int q = 0; q < 6; ++q) {
        float m = fmaxf(fmaxf(a0[2 * q], a0[2 * q + 1]),
                        fmaxf(a1[2 * q], a1[2 * q + 1]));
        pooled[obase + q] = m + bias;
      }
      if (i < 5) {  // slide: load img rows 2*ph+6, 2*ph+7 over the two oldest
        int ir0 = 2 * ph + 6, ir1 = 2 * ph + 7;
        float* d0 = &R[(2 * i) % 6][0];
        float* d1 = &R[(2 * i + 1) % 6][0];
#pragma unroll
        for (int q = 0; q < 4; ++q) {
          ((float4*)d0)[q] = ((const float4*)img)[ir0 * 7 + half * 3 + q];
          ((float4*)d1)[q] = ((const float4*)img)[ir1 * 7 + half * 3 + q];
        }
      }
    }
  }
  __syncthreads();

  // compute this thread's 36 select keys ONCE into registers
  unsigned keys[36];
  {
    const float bcf = bcs[tid >> 2];
#pragma unroll
    for (int e4 = 0; e4 < 9; ++e4) {
      float4 pv = ((float4*)pooled)[tid * 9 + e4];
      keys[4 * e4 + 0] = tokey(pv.x * bcf);
      keys[4 * e4 + 1] = tokey(pv.y * bcf);
      keys[4 * e4 + 2] = tokey(pv.z * bcf);
      keys[4 * e4 + 3] = tokey(pv.w * bcf);
    }
  }

  // radix-select the 400th-largest key; per-wave split histograms + shfl suffix scan
  unsigned kfix = 0;
  unsigned kk = 400;
  for (int pass = 3; pass >= 0; --pass) {
    const int shift = pass * 8;
    const unsigned himask = (pass == 3) ? 0u : (0xFFFFFFFFu << (shift + 8));
#pragma unroll
    for (int w2 = 0; w2 < 4; ++w2) hist4[w2][tid] = 0;
    __syncthreads();
    unsigned* myh = hist4[wv_id];
#pragma unroll
    for (int e = 0; e < 36; ++e) {
      unsigned key = keys[e];
      if (((key ^ kfix) & himask) == 0)
        atomicAdd(&myh[(key >> shift) & 255u], 1u);
    }
    __syncthreads();
    unsigned own = hist4[0][tid] + hist4[1][tid] + hist4[2][tid] + hist4[3][tid];
    unsigned v = own;
#pragma unroll
    for (int off = 1; off < 64; off <<= 1) {
      unsigned y = __shfl_down(v, off, 64);
      if (lane + off < 64) v += y;
    }
    if (lane == 0) wtot[wv_id] = v;
    __syncthreads();
#pragma unroll
    for (int w2 = 0; w2 < 4; ++w2)
      if (w2 > wv_id) v += wtot[w2];
    unsigned snext = v - own;
    if (v >= kk && snext < kk) {
      selb = (unsigned)tid;
      selk = kk - snext;
    }
    __syncthreads();
    kfix |= selb << shift;
    kk = selk;
    __syncthreads();
  }

  // sorted compaction: per-thread count -> shfl prefix scan -> ordered write.
  // keep ALL with key >= kfix (== boosted >= thr bitwise, ties kept like ref)
  unsigned mycnt = 0;
#pragma unroll
  for (int e = 0; e < 36; ++e) mycnt += (keys[e] >= kfix) ? 1u : 0u;
  unsigned px = mycnt;
#pragma unroll
  for (int off = 1; off < 64; off <<= 1) {
    unsigned y = __shfl_up(px, off, 64);
    if (lane >= off) px += y;
  }
  if (lane == 63) wtot[wv_id] = px;
  __syncthreads();
  unsigned base = 0;
#pragma unroll
  for (int w2 = 0; w2 < 4; ++w2)
    if (w2 < wv_id) base += wtot[w2];
  int pos = (int)(base + px - mycnt);  // exclusive prefix
  for (int e = 0; e < 36; ++e) {
    if (keys[e] >= kfix) {
      int o = tid * 36 + e;
      if (pos < 512)
        wpair[b * 512 + pos] = make_int2(__float_as_int(pooled[o]), o << 12);
      ++pos;
    }
  }
  if (tid == 0) {
    unsigned tot = wtot[0] + wtot[1] + wtot[2] + wtot[3];
    wcnt[b] = (int)(tot < 512u ? tot : 512u);
  }
}

// ---------------- k_fc1 v4: float2-paired XCD-sliced sparse fc1 gather ----------------
// Theory: r0/r3 measurements put k_fc1 at ~25 TB/s effective L2 read = 73% of
// the 34.5 TB/s ceiling with one 4B global_load_dword per unit per winner.
// v4 halves the L2 REQUEST count at constant bytes: each lane owns 2 adjacent
// units and loads float2 (8B). 2 waves/block, each wave = one image; slice
// width stays 128 units -> per-XCD L2 working set still 4.7MB and the
// blockIdx&7 XCD swizzle is preserved. Per-unit ascending-k fmaf chain
// unchanged => bit-identical h. Two half-grid dispatches for rocprof
// visibility (pair_base).
__global__ __launch_bounds__(128) void k_fc1(const float* __restrict__ WtF,
                                             const int2* __restrict__ wpair,
                                             const int* __restrict__ wcnt,
                                             const void* __restrict__ fc1b,
                                             float* __restrict__ h,
                                             const int* __restrict__ flag,
                                             int pair_base) {
  __shared__ __align__(16) int2 wl[1024];  // [wave][512]
  const int tid = threadIdx.x;  // 0..127
  const int lane = tid & 63;
  const int wv = tid >> 6;  // 0/1: which image of the pair
  const int img = (pair_base + (int)(blockIdx.x >> 3)) * 2 + wv;
  const int slice = blockIdx.x & 7;
  const int isb = *flag;
  const int cnt = wcnt[img];
  const int2* __restrict__ wp = wpair + img * 512;
  int2* mywl = wl + (wv << 9);
  for (int i = lane; i < cnt; i += 64) mywl[i] = wp[i];
  __syncthreads();
  const int u = (slice << 7) + (lane << 1);  // 2 adjacent units per lane
  const char* __restrict__ Wb = (const char*)WtF + (unsigned)u * 4u;
  const int4* wl4 = (const int4*)mywl;  // 2 pairs per int4, 16B-aligned
  float acc0 = 0.f, acc1 = 0.f;
  int w = 0;
  for (; w + 8 <= cnt; w += 8) {
    const int b4 = w >> 1;
    int4 q0 = wl4[b4 + 0];
    int4 q1 = wl4[b4 + 1];
    int4 q2 = wl4[b4 + 2];
    int4 q3 = wl4[b4 + 3];
    float2 m0 = *(const float2*)(Wb + (unsigned)q0.y);
    float2 m1 = *(const float2*)(Wb + (unsigned)q0.w);
    float2 m2 = *(const float2*)(Wb + (unsigned)q1.y);
    float2 m3 = *(const float2*)(Wb + (unsigned)q1.w);
    float2 m4 = *(const float2*)(Wb + (unsigned)q2.y);
    float2 m5 = *(const float2*)(Wb + (unsigned)q2.w);
    float2 m6 = *(const float2*)(Wb + (unsigned)q3.y);
    float2 m7 = *(const float2*)(Wb + (unsigned)q3.w);
    acc0 = fmaf(__int_as_float(q0.x), m0.x, acc0);
    acc1 = fmaf(__int_as_float(q0.x), m0.y, acc1);
    acc0 = fmaf(__int_as_float(q0.z), m1.x, acc0);
    acc1 = fmaf(__int_as_float(q0.z), m1.y, acc1);
    acc0 = fmaf(__int_as_float(q1.x), m2.x, acc0);
    acc1 = fmaf(__int_as_float(q1.x), m2.y, acc1);
    acc0 = fmaf(__int_as_float(q1.z), m3.x, acc0);
    acc1 = fmaf(__int_as_float(q1.z), m3.y, acc1);
    acc0 = fmaf(__int_as_float(q2.x), m4.x, acc0);
    acc1 = fmaf(__int_as_float(q2.x), m4.y, acc1);
    acc0 = fmaf(__int_as_float(q2.z), m5.x, acc0);
    acc1 = fmaf(__int_as_float(q2.z), m5.y, acc1);
    acc0 = fmaf(__int_as_float(q3.x), m6.x, acc0);
    acc1 = fmaf(__int_as_float(q3.x), m6.y, acc1);
    acc0 = fmaf(__int_as_float(q3.z), m7.x, acc0);
    acc1 = fmaf(__int_as_float(q3.z), m7.y, acc1);
  }
  for (; w < cnt; ++w) {
    int2 p = mywl[w];
    float2 m = *(const float2*)(Wb + (unsigned)p.y);
    acc0 = fmaf(__int_as_float(p.x), m.x, acc0);
    acc1 = fmaf(__int_as_float(p.x), m.y, acc1);
  }
  float2 o;
  o.x = acc0 + gload(fc1b, u, isb);
  o.y = acc1 + gload(fc1b, u + 1, isb);
  *(float2*)(h + img * 1024 + u) = o;
}

// ---------------- k_boost: fc boost factors computed ONCE ----------------
__global__ __launch_bounds__(256) void k_boost(const void* __restrict__ dutyfc,
                                               float* __restrict__ bf,
                                               const int* __restrict__ flag) {
  const int u = blockIdx.x * 256 + threadIdx.x;
  const int isb = *flag;
  if (u < 1024)
    bf[u] = (float)exp((double)(0.09765625f - gload(dutyfc, u, isb)));
}

// ---------------- k_sel: kwinners(k=100, >=thr) + f64 fc2 + log_softmax ----------------
__global__ __launch_bounds__(256) void k_sel(const float* __restrict__ h,
                                             const float* __restrict__ bf,
                                             const void* __restrict__ fc2w,
                                             const void* __restrict__ fc2b,
                                             void* __restrict__ out,
                                             const int* __restrict__ flag) {
  __shared__ unsigned hist4[4][256];
  __shared__ unsigned wtot[4];
  __shared__ unsigned selb, selk;
  __shared__ double lg[10];
  __shared__ double mred[2];
  const int tid = threadIdx.x;
  const int row = blockIdx.x;
  const int isb = *flag;
  const int lane = tid & 63;
  const int wv_id = tid >> 6;
  if (tid < 10) lg[tid] = (double)gload(fc2b, tid, isb);
  __syncthreads();

  const int u0 = 2 * tid, u1 = 2 * tid + 1, u2 = 512 + 2 * tid, u3 = 513 + 2 * tid;
  float2 hlo = ((const float2*)(h + row * 1024))[tid];
  float2 hhi = ((const float2*)(h + row * 1024 + 512))[tid];
  float h0 = hlo.x, h1 = hlo.y, h2 = hhi.x, h3 = hhi.y;
  float2 blo = ((const float2*)bf)[tid];
  float2 bhi = ((const float2*)(bf + 512))[tid];
  unsigned k0 = tokey(h0 * blo.x);
  unsigned k1 = tokey(h1 * blo.y);
  unsigned k2 = tokey(h2 * bhi.x);
  unsigned k3 = tokey(h3 * bhi.y);

  unsigned kfix = 0;
  unsigned kk = 100;
  for (int pass = 3; pass >= 0; --pass) {
    const int shift = pass * 8;
    const unsigned himask = (pass == 3) ? 0u : (0xFFFFFFFFu << (shift + 8));
#pragma unroll
    for (int w2 = 0; w2 < 4; ++w2) hist4[w2][tid] = 0;
    __syncthreads();
    unsigned* myh = hist4[wv_id];
    if (((k0 ^ kfix) & himask) == 0) atomicAdd(&myh[(k0 >> shift) & 255u], 1u);
    if (((k1 ^ kfix) & himask) == 0) atomicAdd(&myh[(k1 >> shift) & 255u], 1u);
    if (((k2 ^ kfix) & himask) == 0) atomicAdd(&myh[(k2 >> shift) & 255u], 1u);
    if (((k3 ^ kfix) & himask) == 0) atomicAdd(&myh[(k3 >> shift) & 255u], 1u);
    __syncthreads();
    unsigned own = hist4[0][tid] + hist4[1][tid] + hist4[2][tid] + hist4[3][tid];
    unsigned v = own;
#pragma unroll
    for (int off = 1; off < 64; off <<= 1) {
      unsigned y = __shfl_down(v, off, 64);
      if (lane + off < 64) v += y;
    }
    if (lane == 0) wtot[wv_id] = v;
    __syncthreads();
#pragma unroll
    for (int w2 = 0; w2 < 4; ++w2)
      if (w2 > wv_id) v += wtot[w2];
    unsigned snext = v - own;
    if (v >= kk && snext < kk) {
      selb = (unsigned)tid;
      selk = kk - snext;
    }
    __syncthreads();
    kfix |= selb << shift;
    kk = selk;
    __syncthreads();
  }
  bool kp0 = k0 >= kfix, kp1 = k1 >= kfix, kp2 = k2 >= kfix, kp3 = k3 >= kfix;

  double part[10];
#pragma unroll
  for (int c = 0; c < 10; ++c) part[c] = 0.0;
  if (kp0) {
#pragma unroll
    for (int c = 0; c < 10; ++c) part[c] = fma((double)h0, (double)gload(fc2w, c * 1024 + u0, isb), part[c]);
  }
  if (kp1) {
#pragma unroll
    for (int c = 0; c < 10; ++c) part[c] = fma((double)h1, (double)gload(fc2w, c * 1024 + u1, isb), part[c]);
  }
  if (kp2) {
#pragma unroll
    for (int c = 0; c < 10; ++c) part[c] = fma((double)h2, (double)gload(fc2w, c * 1024 + u2, isb), part[c]);
  }
  if (kp3) {
#pragma unroll
    for (int c = 0; c < 10; ++c) part[c] = fma((double)h3, (double)gload(fc2w, c * 1024 + u3, isb), part[c]);
  }
#pragma unroll
  for (int c = 0; c < 10; ++c) {
    double p = part[c];
    for (int off = 32; off > 0; off >>= 1) p += __shfl_xor(p, off);
    if ((tid & 63) == 0) atomicAdd(&lg[c], p);
  }
  __syncthreads();
  if (tid == 0) {
    double m = lg[0];
#pragma unroll
    for (int c = 1; c < 10; ++c) m = lg[c] > m ? lg[c] : m;
    double sum = 0.0;
#pragma unroll
    for (int c = 0; c < 10; ++c) sum += exp(lg[c] - m);
    mred[0] = m;
    mred[1] = log(sum);
  }
  __syncthreads();
  if (tid < 10) {
    double o = lg[tid] - mred[0] - mred[1];
    if (isb)
      ((unsigned short*)out)[row * 10 + tid] = f2b((float)o);
    else
      ((float*)out)[row * 10 + tid] = (float)o;
  }
}

// ---------------- launch ----------------
extern "C" void kernel_launch(void* const* d_in, const int* in_sizes, int n_in,
                              void* d_out, int out_size, void* d_ws, size_t ws_size,
                              hipStream_t stream) {
  // ws layout (bytes):
  //   WtF   : 9216*1024*4 = 37,748,736  @ 0   (reused as bf[1024] after k_fc1)
  //   wpair : 4096*512*8  = 16,777,216  @ 37,748,736
  //   wcnt  : 4096*4      =     16,384  @ 54,525,952
  //   h     : 4096*1024*4 = 16,777,216  @ 54,542,336
  //   flag  : 4                         @ 71,319,552
  char* ws = (char*)d_ws;
  float* WtF = (float*)ws;
  int2* wpair = (int2*)(ws + 37748736);
  int* wcnt = (int*)(ws + 54525952);
  float* h = (float*)(ws + 54542336);
  int* flag = (int*)(ws + 71319552);
  float* bf = WtF;  // WtF region is dead after k_fc1

  k_detect<<<1, 64, 0, stream>>>(d_in[0], flag);
  k_prep<<<dim3(144, 16), 256, 0, stream>>>(d_in[4], d_in[5], WtF, flag);
  k_conv<<<4096, 256, 0, stream>>>(d_in[0], d_in[1], d_in[2], d_in[3],
                                   wpair, wcnt, flag);
  k_fc1<<<1024 * 8, 128, 0, stream>>>(WtF, wpair, wcnt, d_in[6], h, flag, 0);
  k_fc1<<<1024 * 8, 128, 0, stream>>>(WtF, wpair, wcnt, d_in[6], h, flag, 1024);
  k_boost<<<4, 256, 0, stream>>>(d_in[7], bf, flag);
  k_sel<<<4096, 256, 0, stream>>>(h, bf, d_in[8], d_in[9], d_out, flag);
}

// Round 8
// 590.487 us; speedup vs baseline: 1.2412x; 1.2412x over previous
//
#include <hip/hip_runtime.h>

// ---------------- dtype helpers ----------------
__device__ __forceinline__ float b2f(unsigned short u) {
  return __uint_as_float(((unsigned)u) << 16);
}
__device__ __forceinline__ unsigned short f2b(float f) {
  unsigned u = __float_as_uint(f);
  return (unsigned short)((u + 0x7FFFu + ((u >> 16) & 1u)) >> 16);
}
// load element i of a tensor that is bf16 (isb=1) or fp32 (isb=0)
__device__ __forceinline__ float gload(const void* p, int i, int isb) {
  return isb ? b2f(((const unsigned short*)p)[i]) : ((const float*)p)[i];
}
// monotone bijection float -> uint32 (order-preserving incl. negatives)
__device__ __forceinline__ unsigned tokey(float f) {
  unsigned u = __float_as_uint(f);
  return u ^ (unsigned)(((int)u >> 31) | 0x80000000u);
}

// ---------------- dtype detector (dataset proven fp32; kept for safety) ----------------
__global__ void k_detect(const void* x, int* flag) {
  int tid = threadIdx.x;  // 1 wave
  unsigned short u = ((const unsigned short*)x)[2 * tid];
  int e = (u >> 7) & 0xFF;
  bool sane = (e >= 100 && e <= 140);
  unsigned long long m = __ballot(sane);
  if (tid == 0) *flag = (__popcll(m) >= 40) ? 1 : 0;
}

// ---------------- k_prep: WtF[i][u] = fc1_w[u][i] * (mask<0.5), f32 transposed ----------------
__global__ __launch_bounds__(256) void k_prep(const void* __restrict__ fc1w,
                                              const void* __restrict__ mraw,
                                              float* __restrict__ WtF,
                                              const int* __restrict__ flag) {
  __shared__ float tile[64][65];
  const int isb = *flag;
  const int i0 = blockIdx.x * 64;  // K index (9216)
  const int u0 = blockIdx.y * 64;  // unit index (1024)
  const int tx = threadIdx.x & 63, ty = threadIdx.x >> 6;
  for (int uu = ty; uu < 64; uu += 4) {
    int gi = (u0 + uu) * 9216 + i0 + tx;
    float wv = gload(fc1w, gi, isb);
    float mv = gload(mraw, gi, isb);
    tile[uu][tx] = (mv < 0.5f) ? wv : 0.0f;
  }
  __syncthreads();
  for (int ii = ty; ii < 64; ii += 4)
    WtF[(i0 + ii) * 1024 + u0 + tx] = tile[tx][ii];
}

// ---------------- k_conv: conv5x5 + pool + radix kwinners ----------------
// r3-proven base (204us, VGPR 80, zero spill). v8 changes, both static-index
// safe (v5/v6 autopsies: RUNTIME indexing of keys[] -> scratch spill; run-
// length aggregation itself is sequential-static):
//  (a) pass-3 histogram atomics run-length aggregated: neighboring pooled
//      pixels (same channel+boost) often share the top key byte -> 9216
//      same-bin LDS atomics/block shrink ~2-3x (they are the bulk of
//      SQ_LDS_BANK_CONFLICT = 2.19e7).
//  (b) 5th barrier per radix pass removed: the next pass's zero->sync
//      already orders selb/selk reuse (every thread passes the zero-barrier,
//      which waits on all selb readers, before any thread rewrites selb).
__global__ __launch_bounds__(256) void k_conv(const void* __restrict__ x,
                                              const void* __restrict__ c1w_g,
                                              const void* __restrict__ c1b_g,
                                              const void* __restrict__ duty_g,
                                              int2* __restrict__ wpair,
                                              int* __restrict__ wcnt,
                                              const int* __restrict__ flag) {
  __shared__ __align__(16) float img[784];
  __shared__ float cw[1600];
  __shared__ float cb[64], bcs[64];
  __shared__ __align__(16) float pooled[9216];
  __shared__ unsigned hist4[4][256];
  __shared__ unsigned wtot[4];
  __shared__ unsigned selb, selk;
  const int tid = threadIdx.x;
  const int b = blockIdx.x;
  const int isb = *flag;
  const int lane = tid & 63;
  const int wv_id = tid >> 6;

  for (int i = tid; i < 784; i += 256) img[i] = gload(x, b * 784 + i, isb);
  for (int i = tid; i < 1600; i += 256) cw[i] = gload(c1w_g, i, isb);
  if (tid < 64) {
    cb[tid] = gload(c1b_g, tid, isb);
    float arg = (float)(400.0 / 9216.0) - gload(duty_g, tid, isb);
    bcs[tid] = (float)exp((double)arg);
  }
  __syncthreads();

  // mapping: c = tid>>2 (64), half = tid&1 (2), pg = (tid>>1)&1 (2) -> ph0 = pg*6
  {
    const int c = tid >> 2;
    const int half = tid & 1;
    const int ph0 = ((tid >> 1) & 1) * 6;
    float w[25];
#pragma unroll
    for (int i = 0; i < 25; ++i) w[i] = cw[c * 25 + i];
    const float bias = cb[c];
    float R[6][16];
#pragma unroll
    for (int r = 0; r < 6; ++r) {
      int ir = 2 * ph0 + r;
#pragma unroll
      for (int q = 0; q < 4; ++q)
        ((float4*)&R[r][0])[q] = ((const float4*)img)[ir * 7 + half * 3 + q];
    }
#pragma unroll
    for (int i = 0; i < 6; ++i) {
      const int ph = ph0 + i;
      float a0[12], a1[12];
#pragma unroll
      for (int j = 0; j < 12; ++j) { a0[j] = 0.f; a1[j] = 0.f; }
      // single sequential fmaf chain per conv cell, k = kw*5 + kh order
      // (kh fastest -- Eigen patch linearization) => bit-exact vs reference
#pragma unroll
      for (int kj = 0; kj < 5; ++kj) {       // kw OUTER
#pragma unroll
        for (int kr = 0; kr < 5; ++kr) {     // kh INNER (fastest)
          float wk = w[kr * 5 + kj];
          const float* r0 = &R[(2 * i + kr) % 6][0];
          const float* r1 = &R[(2 * i + kr + 1) % 6][0];
#pragma unroll
          for (int j = 0; j < 12; ++j) {
            a0[j] = fmaf(r0[j + kj], wk, a0[j]);
            a1[j] = fmaf(r1[j + kj], wk, a1[j]);
          }
        }
      }
      int obase = c * 144 + ph * 12 + half * 6;
#pragma unroll
      for (int q = 0; q < 6; ++q) {
        float m = fmaxf(fmaxf(a0[2 * q], a0[2 * q + 1]),
                        fmaxf(a1[2 * q], a1[2 * q + 1]));
        pooled[obase + q] = m + bias;
      }
      if (i < 5) {  // slide: load img rows 2*ph+6, 2*ph+7 over the two oldest
        int ir0 = 2 * ph + 6, ir1 = 2 * ph + 7;
        float* d0 = &R[(2 * i) % 6][0];
        float* d1 = &R[(2 * i + 1) % 6][0];
#pragma unroll
        for (int q = 0; q < 4; ++q) {
          ((float4*)d0)[q] = ((const float4*)img)[ir0 * 7 + half * 3 + q];
          ((float4*)d1)[q] = ((const float4*)img)[ir1 * 7 + half * 3 + q];
        }
      }
    }
  }
  __syncthreads();

  // compute this thread's 36 select keys ONCE into registers
  unsigned keys[36];
  {
    const float bcf = bcs[tid >> 2];
#pragma unroll
    for (int e4 = 0; e4 < 9; ++e4) {
      float4 pv = ((float4*)pooled)[tid * 9 + e4];
      keys[4 * e4 + 0] = tokey(pv.x * bcf);
      keys[4 * e4 + 1] = tokey(pv.y * bcf);
      keys[4 * e4 + 2] = tokey(pv.z * bcf);
      keys[4 * e4 + 3] = tokey(pv.w * bcf);
    }
  }

  // radix-select the 400th-largest key; per-wave split histograms + shfl suffix scan
  unsigned kfix = 0;
  unsigned kk = 400;
  for (int pass = 3; pass >= 0; --pass) {
    const int shift = pass * 8;
    const unsigned himask = (pass == 3) ? 0u : (0xFFFFFFFFu << (shift + 8));
#pragma unroll
    for (int w2 = 0; w2 < 4; ++w2) hist4[w2][tid] = 0;
    __syncthreads();
    unsigned* myh = hist4[wv_id];
    if (pass == 3) {
      // run-length aggregated (all-static indices; scalars only)
      unsigned cbin = keys[0] >> 24, ccnt = 1;
#pragma unroll
      for (int e = 1; e < 36; ++e) {
        unsigned bin = keys[e] >> 24;
        if (bin == cbin) {
          ++ccnt;
        } else {
          atomicAdd(&myh[cbin], ccnt);
          cbin = bin;
          ccnt = 1;
        }
      }
      atomicAdd(&myh[cbin], ccnt);
    } else {
#pragma unroll
      for (int e = 0; e < 36; ++e) {
        unsigned key = keys[e];
        if (((key ^ kfix) & himask) == 0)
          atomicAdd(&myh[(key >> shift) & 255u], 1u);
      }
    }
    __syncthreads();
    unsigned own = hist4[0][tid] + hist4[1][tid] + hist4[2][tid] + hist4[3][tid];
    unsigned v = own;
#pragma unroll
    for (int off = 1; off < 64; off <<= 1) {
      unsigned y = __shfl_down(v, off, 64);
      if (lane + off < 64) v += y;
    }
    if (lane == 0) wtot[wv_id] = v;
    __syncthreads();
#pragma unroll
    for (int w2 = 0; w2 < 4; ++w2)
      if (w2 > wv_id) v += wtot[w2];
    unsigned snext = v - own;
    if (v >= kk && snext < kk) {
      selb = (unsigned)tid;
      selk = kk - snext;
    }
    __syncthreads();
    kfix |= selb << shift;
    kk = selk;
    // (5th barrier removed: next pass's zero->sync orders selb/selk reuse)
  }

  // sorted compaction: per-thread count -> shfl prefix scan -> ordered write.
  // keep ALL with key >= kfix (== boosted >= thr bitwise, ties kept like ref)
  unsigned mycnt = 0;
#pragma unroll
  for (int e = 0; e < 36; ++e) mycnt += (keys[e] >= kfix) ? 1u : 0u;
  unsigned px = mycnt;
#pragma unroll
  for (int off = 1; off < 64; off <<= 1) {
    unsigned y = __shfl_up(px, off, 64);
    if (lane >= off) px += y;
  }
  if (lane == 63) wtot[wv_id] = px;
  __syncthreads();
  unsigned base = 0;
#pragma unroll
  for (int w2 = 0; w2 < 4; ++w2)
    if (w2 < wv_id) base += wtot[w2];
  int pos = (int)(base + px - mycnt);  // exclusive prefix
  for (int e = 0; e < 36; ++e) {
    if (keys[e] >= kfix) {
      int o = tid * 36 + e;
      if (pos < 512)
        wpair[b * 512 + pos] = make_int2(__float_as_int(pooled[o]), o << 12);
      ++pos;
    }
  }
  if (tid == 0) {
    unsigned tot = wtot[0] + wtot[1] + wtot[2] + wtot[3];
    wcnt[b] = (int)(tot < 512u ? tot : 512u);
  }
}

// ---------------- k_fc1: XCD-sliced sparse fc1 gather (r3-proven form) ----------------
// Structure optimum per two failed experiments: scalar s_load path (+10us, r2)
// and float2 2-unit lanes (+55us/dispatch, r7 -- halved thread count halved
// MLP; the gather is latency x parallelism bound). Keep: max threads, 1 unit
// per lane, LDS-staged winner list, 8-pair int4 unroll so 8 independent
// global_load_dword issue ahead of the serial fmac chain. Ascending-w single
// f32 fmaf chain per unit => bit-identical h. Half-grid x2 for rocprof
// visibility.
__global__ __launch_bounds__(128) void k_fc1(const float* __restrict__ WtF,
                                             const int2* __restrict__ wpair,
                                             const int* __restrict__ wcnt,
                                             const void* __restrict__ fc1b,
                                             float* __restrict__ h,
                                             const int* __restrict__ flag,
                                             int img_base) {
  __shared__ __align__(16) int2 wl[512];
  const int tid = threadIdx.x;  // 0..127
  const int img = img_base + (blockIdx.x >> 3);
  const int slice = blockIdx.x & 7;
  const int isb = *flag;
  const int cnt = wcnt[img];
  const int2* __restrict__ wp = wpair + img * 512;
  for (int i = tid; i < cnt; i += 128) wl[i] = wp[i];
  __syncthreads();
  const int u = (slice << 7) + tid;
  const char* __restrict__ Wb = (const char*)WtF + (unsigned)u * 4u;
  const int4* wl4 = (const int4*)wl;  // 2 pairs per int4, 16B-aligned
  float acc = 0.f;
  int w = 0;
  for (; w + 8 <= cnt; w += 8) {
    const int b4 = w >> 1;
    int4 q0 = wl4[b4 + 0];
    int4 q1 = wl4[b4 + 1];
    int4 q2 = wl4[b4 + 2];
    int4 q3 = wl4[b4 + 3];
    acc = fmaf(__int_as_float(q0.x), *(const float*)(Wb + (unsigned)q0.y), acc);
    acc = fmaf(__int_as_float(q0.z), *(const float*)(Wb + (unsigned)q0.w), acc);
    acc = fmaf(__int_as_float(q1.x), *(const float*)(Wb + (unsigned)q1.y), acc);
    acc = fmaf(__int_as_float(q1.z), *(const float*)(Wb + (unsigned)q1.w), acc);
    acc = fmaf(__int_as_float(q2.x), *(const float*)(Wb + (unsigned)q2.y), acc);
    acc = fmaf(__int_as_float(q2.z), *(const float*)(Wb + (unsigned)q2.w), acc);
    acc = fmaf(__int_as_float(q3.x), *(const float*)(Wb + (unsigned)q3.y), acc);
    acc = fmaf(__int_as_float(q3.z), *(const float*)(Wb + (unsigned)q3.w), acc);
  }
  for (; w < cnt; ++w) {
    int2 p = wl[w];
    acc = fmaf(__int_as_float(p.x), *(const float*)(Wb + (unsigned)p.y), acc);
  }
  h[img * 1024 + u] = acc + gload(fc1b, u, isb);
}

// ---------------- k_boost: fc boost factors computed ONCE ----------------
__global__ __launch_bounds__(256) void k_boost(const void* __restrict__ dutyfc,
                                               float* __restrict__ bf,
                                               const int* __restrict__ flag) {
  const int u = blockIdx.x * 256 + threadIdx.x;
  const int isb = *flag;
  if (u < 1024)
    bf[u] = (float)exp((double)(0.09765625f - gload(dutyfc, u, isb)));
}

// ---------------- k_sel: kwinners(k=100, >=thr) + f64 fc2 + log_softmax ----------------
// (r3-proven + the same 5th-barrier removal as k_conv, same ordering proof)
__global__ __launch_bounds__(256) void k_sel(const float* __restrict__ h,
                                             const float* __restrict__ bf,
                                             const void* __restrict__ fc2w,
                                             const void* __restrict__ fc2b,
                                             void* __restrict__ out,
                                             const int* __restrict__ flag) {
  __shared__ unsigned hist4[4][256];
  __shared__ unsigned wtot[4];
  __shared__ unsigned selb, selk;
  __shared__ double lg[10];
  __shared__ double mred[2];
  const int tid = threadIdx.x;
  const int row = blockIdx.x;
  const int isb = *flag;
  const int lane = tid & 63;
  const int wv_id = tid >> 6;
  if (tid < 10) lg[tid] = (double)gload(fc2b, tid, isb);
  __syncthreads();

  const int u0 = 2 * tid, u1 = 2 * tid + 1, u2 = 512 + 2 * tid, u3 = 513 + 2 * tid;
  float2 hlo = ((const float2*)(h + row * 1024))[tid];
  float2 hhi = ((const float2*)(h + row * 1024 + 512))[tid];
  float h0 = hlo.x, h1 = hlo.y, h2 = hhi.x, h3 = hhi.y;
  float2 blo = ((const float2*)bf)[tid];
  float2 bhi = ((const float2*)(bf + 512))[tid];
  unsigned k0 = tokey(h0 * blo.x);
  unsigned k1 = tokey(h1 * blo.y);
  unsigned k2 = tokey(h2 * bhi.x);
  unsigned k3 = tokey(h3 * bhi.y);

  unsigned kfix = 0;
  unsigned kk = 100;
  for (int pass = 3; pass >= 0; --pass) {
    const int shift = pass * 8;
    const unsigned himask = (pass == 3) ? 0u : (0xFFFFFFFFu << (shift + 8));
#pragma unroll
    for (int w2 = 0; w2 < 4; ++w2) hist4[w2][tid] = 0;
    __syncthreads();
    unsigned* myh = hist4[wv_id];
    if (((k0 ^ kfix) & himask) == 0) atomicAdd(&myh[(k0 >> shift) & 255u], 1u);
    if (((k1 ^ kfix) & himask) == 0) atomicAdd(&myh[(k1 >> shift) & 255u], 1u);
    if (((k2 ^ kfix) & himask) == 0) atomicAdd(&myh[(k2 >> shift) & 255u], 1u);
    if (((k3 ^ kfix) & himask) == 0) atomicAdd(&myh[(k3 >> shift) & 255u], 1u);
    __syncthreads();
    unsigned own = hist4[0][tid] + hist4[1][tid] + hist4[2][tid] + hist4[3][tid];
    unsigned v = own;
#pragma unroll
    for (int off = 1; off < 64; off <<= 1) {
      unsigned y = __shfl_down(v, off, 64);
      if (lane + off < 64) v += y;
    }
    if (lane == 0) wtot[wv_id] = v;
    __syncthreads();
#pragma unroll
    for (int w2 = 0; w2 < 4; ++w2)
      if (w2 > wv_id) v += wtot[w2];
    unsigned snext = v - own;
    if (v >= kk && snext < kk) {
      selb = (unsigned)tid;
      selk = kk - snext;
    }
    __syncthreads();
    kfix |= selb << shift;
    kk = selk;
    // (5th barrier removed; next pass's zero->sync orders reuse)
  }
  bool kp0 = k0 >= kfix, kp1 = k1 >= kfix, kp2 = k2 >= kfix, kp3 = k3 >= kfix;

  double part[10];
#pragma unroll
  for (int c = 0; c < 10; ++c) part[c] = 0.0;
  if (kp0) {
#pragma unroll
    for (int c = 0; c < 10; ++c) part[c] = fma((double)h0, (double)gload(fc2w, c * 1024 + u0, isb), part[c]);
  }
  if (kp1) {
#pragma unroll
    for (int c = 0; c < 10; ++c) part[c] = fma((double)h1, (double)gload(fc2w, c * 1024 + u1, isb), part[c]);
  }
  if (kp2) {
#pragma unroll
    for (int c = 0; c < 10; ++c) part[c] = fma((double)h2, (double)gload(fc2w, c * 1024 + u2, isb), part[c]);
  }
  if (kp3) {
#pragma unroll
    for (int c = 0; c < 10; ++c) part[c] = fma((double)h3, (double)gload(fc2w, c * 1024 + u3, isb), part[c]);
  }
#pragma unroll
  for (int c = 0; c < 10; ++c) {
    double p = part[c];
    for (int off = 32; off > 0; off >>= 1) p += __shfl_xor(p, off);
    if ((tid & 63) == 0) atomicAdd(&lg[c], p);
  }
  __syncthreads();
  if (tid == 0) {
    double m = lg[0];
#pragma unroll
    for (int c = 1; c < 10; ++c) m = lg[c] > m ? lg[c] : m;
    double sum = 0.0;
#pragma unroll
    for (int c = 0; c < 10; ++c) sum += exp(lg[c] - m);
    mred[0] = m;
    mred[1] = log(sum);
  }
  __syncthreads();
  if (tid < 10) {
    double o = lg[tid] - mred[0] - mred[1];
    if (isb)
      ((unsigned short*)out)[row * 10 + tid] = f2b((float)o);
    else
      ((float*)out)[row * 10 + tid] = (float)o;
  }
}

// ---------------- launch ----------------
extern "C" void kernel_launch(void* const* d_in, const int* in_sizes, int n_in,
                              void* d_out, int out_size, void* d_ws, size_t ws_size,
                              hipStream_t stream) {
  // ws layout (bytes):
  //   WtF   : 9216*1024*4 = 37,748,736  @ 0   (reused as bf[1024] after k_fc1)
  //   wpair : 4096*512*8  = 16,777,216  @ 37,748,736
  //   wcnt  : 4096*4      =     16,384  @ 54,525,952
  //   h     : 4096*1024*4 = 16,777,216  @ 54,542,336
  //   flag  : 4                         @ 71,319,552
  char* ws = (char*)d_ws;
  float* WtF = (float*)ws;
  int2* wpair = (int2*)(ws + 37748736);
  int* wcnt = (int*)(ws + 54525952);
  float* h = (float*)(ws + 54542336);
  int* flag = (int*)(ws + 71319552);
  float* bf = WtF;  // WtF region is dead after k_fc1

  k_detect<<<1, 64, 0, stream>>>(d_in[0], flag);
  k_prep<<<dim3(144, 16), 256, 0, stream>>>(d_in[4], d_in[5], WtF, flag);
  k_conv<<<4096, 256, 0, stream>>>(d_in[0], d_in[1], d_in[2], d_in[3],
                                   wpair, wcnt, flag);
  k_fc1<<<2048 * 8, 128, 0, stream>>>(WtF, wpair, wcnt, d_in[6], h, flag, 0);
  k_fc1<<<2048 * 8, 128, 0, stream>>>(WtF, wpair, wcnt, d_in[6], h, flag, 2048);
  k_boost<<<4, 256, 0, stream>>>(d_in[7], bf, flag);
  k_sel<<<4096, 256, 0, stream>>>(h, bf, d_in[8], d_in[9], d_out, flag);
}

// Round 9
// 588.326 us; speedup vs baseline: 1.2458x; 1.0037x over previous
//
#include <hip/hip_runtime.h>

// ---------------- dtype helpers ----------------
__device__ __forceinline__ float b2f(unsigned short u) {
  return __uint_as_float(((unsigned)u) << 16);
}
__device__ __forceinline__ unsigned short f2b(float f) {
  unsigned u = __float_as_uint(f);
  return (unsigned short)((u + 0x7FFFu + ((u >> 16) & 1u)) >> 16);
}
// load element i of a tensor that is bf16 (isb=1) or fp32 (isb=0)
__device__ __forceinline__ float gload(const void* p, int i, int isb) {
  return isb ? b2f(((const unsigned short*)p)[i]) : ((const float*)p)[i];
}
// monotone bijection float -> uint32 (order-preserving incl. negatives)
__device__ __forceinline__ unsigned tokey(float f) {
  unsigned u = __float_as_uint(f);
  return u ^ (unsigned)(((int)u >> 31) | 0x80000000u);
}

// ---------------- dtype detector (dataset proven fp32; kept for safety) ----------------
__global__ void k_detect(const void* x, int* flag) {
  int tid = threadIdx.x;  // 1 wave
  unsigned short u = ((const unsigned short*)x)[2 * tid];
  int e = (u >> 7) & 0xFF;
  bool sane = (e >= 100 && e <= 140);
  unsigned long long m = __ballot(sane);
  if (tid == 0) *flag = (__popcll(m) >= 40) ? 1 : 0;
}

// ---------------- k_prep: WtF[i][u] = fc1_w[u][i] * (mask<0.5), f32 transposed ----------------
__global__ __launch_bounds__(256) void k_prep(const void* __restrict__ fc1w,
                                              const void* __restrict__ mraw,
                                              float* __restrict__ WtF,
                                              const int* __restrict__ flag) {
  __shared__ float tile[64][65];
  const int isb = *flag;
  const int i0 = blockIdx.x * 64;  // K index (9216)
  const int u0 = blockIdx.y * 64;  // unit index (1024)
  const int tx = threadIdx.x & 63, ty = threadIdx.x >> 6;
  for (int uu = ty; uu < 64; uu += 4) {
    int gi = (u0 + uu) * 9216 + i0 + tx;
    float wv = gload(fc1w, gi, isb);
    float mv = gload(mraw, gi, isb);
    tile[uu][tx] = (mv < 0.5f) ? wv : 0.0f;
  }
  __syncthreads();
  for (int ii = ty; ii < 64; ii += 4)
    WtF[(i0 + ii) * 1024 + u0 + tx] = tile[tx][ii];
}

// ---------------- k_conv: conv5x5 + pool + radix kwinners ----------------
// v9 (on the r8 WIN: 168us, VALUBusy 89%, occupancy 31.6% = 3 blocks/CU on
// 51.2KB LDS). Occupancy 3->4 blocks WITHOUT touching the conv inner loop
// (v5/v6 autopsies: perturbing it spills):
//  (a) hist2[2][256] OVERLAID into img[784]'s LDS (img dead after the
//      post-conv barrier; hist written only after it -> disjoint lifetimes).
//  (b) cw staging dropped: each thread loads its w[25] from global (6.4KB,
//      L1-resident across the 4 resident blocks). img staging KEPT so the
//      VGPR-80 conv allocation is unchanged.
//  LDS: pooled 36864 + img/hist union 3136 + cb/bcs 512 + misc 24 = 40536
//  <= 40960 -> 4 blocks/CU (16 waves, +33% latency hiding).
//  __launch_bounds__(256,4): allocator targets 4 waves/EU (VGPR cap 128).
//  Accepted cost: pass-3 run-length atomics share 2 hists (was 4) -> ~2x
//  per-bin contention on ~1/3 the atomics.
__global__ __launch_bounds__(256, 4) void k_conv(const void* __restrict__ x,
                                                 const void* __restrict__ c1w_g,
                                                 const void* __restrict__ c1b_g,
                                                 const void* __restrict__ duty_g,
                                                 int2* __restrict__ wpair,
                                                 int* __restrict__ wcnt,
                                                 const int* __restrict__ flag) {
  // img[784] floats (3136B) unioned with hist2[2][256] (2048B): img is dead
  // after the post-conv __syncthreads; hist writes all come after it.
  __shared__ __align__(16) unsigned char u_imghist[3136];
  __shared__ float cb[64], bcs[64];
  __shared__ __align__(16) float pooled[9216];
  __shared__ unsigned wtot[4];
  __shared__ unsigned selb, selk;
  float* img = (float*)u_imghist;
  unsigned* h2a = (unsigned*)u_imghist;           // hist2[0]
  unsigned* h2b = (unsigned*)(u_imghist + 1024);  // hist2[1]
  const int tid = threadIdx.x;
  const int b = blockIdx.x;
  const int isb = *flag;
  const int lane = tid & 63;
  const int wv_id = tid >> 6;

  for (int i = tid; i < 784; i += 256) img[i] = gload(x, b * 784 + i, isb);
  if (tid < 64) {
    cb[tid] = gload(c1b_g, tid, isb);
    float arg = (float)(400.0 / 9216.0) - gload(duty_g, tid, isb);
    bcs[tid] = (float)exp((double)arg);
  }
  __syncthreads();

  // mapping: c = tid>>2 (64), half = tid&1 (2), pg = (tid>>1)&1 (2) -> ph0 = pg*6
  {
    const int c = tid >> 2;
    const int half = tid & 1;
    const int ph0 = ((tid >> 1) & 1) * 6;
    float w[25];
#pragma unroll
    for (int i = 0; i < 25; ++i) w[i] = gload(c1w_g, c * 25 + i, isb);
    const float bias = cb[c];
    float R[6][16];
#pragma unroll
    for (int r = 0; r < 6; ++r) {
      int ir = 2 * ph0 + r;
#pragma unroll
      for (int q = 0; q < 4; ++q)
        ((float4*)&R[r][0])[q] = ((const float4*)img)[ir * 7 + half * 3 + q];
    }
#pragma unroll
    for (int i = 0; i < 6; ++i) {
      const int ph = ph0 + i;
      float a0[12], a1[12];
#pragma unroll
      for (int j = 0; j < 12; ++j) { a0[j] = 0.f; a1[j] = 0.f; }
      // single sequential fmaf chain per conv cell, k = kw*5 + kh order
      // (kh fastest -- Eigen patch linearization) => bit-exact vs reference
#pragma unroll
      for (int kj = 0; kj < 5; ++kj) {       // kw OUTER
#pragma unroll
        for (int kr = 0; kr < 5; ++kr) {     // kh INNER (fastest)
          float wk = w[kr * 5 + kj];
          const float* r0 = &R[(2 * i + kr) % 6][0];
          const float* r1 = &R[(2 * i + kr + 1) % 6][0];
#pragma unroll
          for (int j = 0; j < 12; ++j) {
            a0[j] = fmaf(r0[j + kj], wk, a0[j]);
            a1[j] = fmaf(r1[j + kj], wk, a1[j]);
          }
        }
      }
      int obase = c * 144 + ph * 12 + half * 6;
#pragma unroll
      for (int q = 0; q < 6; ++q) {
        float m = fmaxf(fmaxf(a0[2 * q], a0[2 * q + 1]),
                        fmaxf(a1[2 * q], a1[2 * q + 1]));
        pooled[obase + q] = m + bias;
      }
      if (i < 5) {  // slide: load img rows 2*ph+6, 2*ph+7 over the two oldest
        int ir0 = 2 * ph + 6, ir1 = 2 * ph + 7;
        float* d0 = &R[(2 * i) % 6][0];
        float* d1 = &R[(2 * i + 1) % 6][0];
#pragma unroll
        for (int q = 0; q < 4; ++q) {
          ((float4*)d0)[q] = ((const float4*)img)[ir0 * 7 + half * 3 + q];
          ((float4*)d1)[q] = ((const float4*)img)[ir1 * 7 + half * 3 + q];
        }
      }
    }
  }
  __syncthreads();  // after this barrier img is DEAD -> its LDS becomes hist2

  // compute this thread's 36 select keys ONCE into registers
  unsigned keys[36];
  {
    const float bcf = bcs[tid >> 2];
#pragma unroll
    for (int e4 = 0; e4 < 9; ++e4) {
      float4 pv = ((float4*)pooled)[tid * 9 + e4];
      keys[4 * e4 + 0] = tokey(pv.x * bcf);
      keys[4 * e4 + 1] = tokey(pv.y * bcf);
      keys[4 * e4 + 2] = tokey(pv.z * bcf);
      keys[4 * e4 + 3] = tokey(pv.w * bcf);
    }
  }

  // radix-select the 400th-largest key; 2 split histograms + shfl suffix scan
  unsigned kfix = 0;
  unsigned kk = 400;
  for (int pass = 3; pass >= 0; --pass) {
    const int shift = pass * 8;
    const unsigned himask = (pass == 3) ? 0u : (0xFFFFFFFFu << (shift + 8));
    h2a[tid] = 0;
    h2b[tid] = 0;
    __syncthreads();
    unsigned* myh = (wv_id < 2) ? h2a : h2b;
    if (pass == 3) {
      // run-length aggregated (all-static indices; scalars only)
      unsigned cbin = keys[0] >> 24, ccnt = 1;
#pragma unroll
      for (int e = 1; e < 36; ++e) {
        unsigned bin = keys[e] >> 24;
        if (bin == cbin) {
          ++ccnt;
        } else {
          atomicAdd(&myh[cbin], ccnt);
          cbin = bin;
          ccnt = 1;
        }
      }
      atomicAdd(&myh[cbin], ccnt);
    } else {
#pragma unroll
      for (int e = 0; e < 36; ++e) {
        unsigned key = keys[e];
        if (((key ^ kfix) & himask) == 0)
          atomicAdd(&myh[(key >> shift) & 255u], 1u);
      }
    }
    __syncthreads();
    unsigned own = h2a[tid] + h2b[tid];
    unsigned v = own;
#pragma unroll
    for (int off = 1; off < 64; off <<= 1) {
      unsigned y = __shfl_down(v, off, 64);
      if (lane + off < 64) v += y;
    }
    if (lane == 0) wtot[wv_id] = v;
    __syncthreads();
#pragma unroll
    for (int w2 = 0; w2 < 4; ++w2)
      if (w2 > wv_id) v += wtot[w2];
    unsigned snext = v - own;
    if (v >= kk && snext < kk) {
      selb = (unsigned)tid;
      selk = kk - snext;
    }
    __syncthreads();
    kfix |= selb << shift;
    kk = selk;
    // (5th barrier removed: next pass's zero->sync orders selb/selk reuse)
  }

  // sorted compaction: per-thread count -> shfl prefix scan -> ordered write.
  // keep ALL with key >= kfix (== boosted >= thr bitwise, ties kept like ref)
  unsigned mycnt = 0;
#pragma unroll
  for (int e = 0; e < 36; ++e) mycnt += (keys[e] >= kfix) ? 1u : 0u;
  unsigned px = mycnt;
#pragma unroll
  for (int off = 1; off < 64; off <<= 1) {
    unsigned y = __shfl_up(px, off, 64);
    if (lane >= off) px += y;
  }
  if (lane == 63) wtot[wv_id] = px;
  __syncthreads();
  unsigned base = 0;
#pragma unroll
  for (int w2 = 0; w2 < 4; ++w2)
    if (w2 < wv_id) base += wtot[w2];
  int pos = (int)(base + px - mycnt);  // exclusive prefix
  for (int e = 0; e < 36; ++e) {
    if (keys[e] >= kfix) {
      int o = tid * 36 + e;
      if (pos < 512)
        wpair[b * 512 + pos] = make_int2(__float_as_int(pooled[o]), o << 12);
      ++pos;
    }
  }
  if (tid == 0) {
    unsigned tot = wtot[0] + wtot[1] + wtot[2] + wtot[3];
    wcnt[b] = (int)(tot < 512u ? tot : 512u);
  }
}

// ---------------- k_fc1: XCD-sliced sparse fc1 gather (r3-proven form) ----------------
// Structure optimum per three convergent experiments: scalar s_load (+10us,
// r2), float2 2-unit lanes (+55us/dispatch, r7 -- halved thread count halved
// MLP). Keep: max threads, 1 unit/lane, LDS-staged winner list, 8-pair int4
// unroll. Ascending-w single f32 fmaf chain per unit => bit-identical h.
__global__ __launch_bounds__(128) void k_fc1(const float* __restrict__ WtF,
                                             const int2* __restrict__ wpair,
                                             const int* __restrict__ wcnt,
                                             const void* __restrict__ fc1b,
                                             float* __restrict__ h,
                                             const int* __restrict__ flag,
                                             int img_base) {
  __shared__ __align__(16) int2 wl[512];
  const int tid = threadIdx.x;  // 0..127
  const int img = img_base + (blockIdx.x >> 3);
  const int slice = blockIdx.x & 7;
  const int isb = *flag;
  const int cnt = wcnt[img];
  const int2* __restrict__ wp = wpair + img * 512;
  for (int i = tid; i < cnt; i += 128) wl[i] = wp[i];
  __syncthreads();
  const int u = (slice << 7) + tid;
  const char* __restrict__ Wb = (const char*)WtF + (unsigned)u * 4u;
  const int4* wl4 = (const int4*)wl;  // 2 pairs per int4, 16B-aligned
  float acc = 0.f;
  int w = 0;
  for (; w + 8 <= cnt; w += 8) {
    const int b4 = w >> 1;
    int4 q0 = wl4[b4 + 0];
    int4 q1 = wl4[b4 + 1];
    int4 q2 = wl4[b4 + 2];
    int4 q3 = wl4[b4 + 3];
    acc = fmaf(__int_as_float(q0.x), *(const float*)(Wb + (unsigned)q0.y), acc);
    acc = fmaf(__int_as_float(q0.z), *(const float*)(Wb + (unsigned)q0.w), acc);
    acc = fmaf(__int_as_float(q1.x), *(const float*)(Wb + (unsigned)q1.y), acc);
    acc = fmaf(__int_as_float(q1.z), *(const float*)(Wb + (unsigned)q1.w), acc);
    acc = fmaf(__int_as_float(q2.x), *(const float*)(Wb + (unsigned)q2.y), acc);
    acc = fmaf(__int_as_float(q2.z), *(const float*)(Wb + (unsigned)q2.w), acc);
    acc = fmaf(__int_as_float(q3.x), *(const float*)(Wb + (unsigned)q3.y), acc);
    acc = fmaf(__int_as_float(q3.z), *(const float*)(Wb + (unsigned)q3.w), acc);
  }
  for (; w < cnt; ++w) {
    int2 p = wl[w];
    acc = fmaf(__int_as_float(p.x), *(const float*)(Wb + (unsigned)p.y), acc);
  }
  h[img * 1024 + u] = acc + gload(fc1b, u, isb);
}

// ---------------- k_boost: fc boost factors computed ONCE ----------------
__global__ __launch_bounds__(256) void k_boost(const void* __restrict__ dutyfc,
                                               float* __restrict__ bf,
                                               const int* __restrict__ flag) {
  const int u = blockIdx.x * 256 + threadIdx.x;
  const int isb = *flag;
  if (u < 1024)
    bf[u] = (float)exp((double)(0.09765625f - gload(dutyfc, u, isb)));
}

// ---------------- k_sel: kwinners(k=100, >=thr) + f64 fc2 + log_softmax ----------------
// (r8-proven: split hists + wave scan + 4-barrier radix)
__global__ __launch_bounds__(256) void k_sel(const float* __restrict__ h,
                                             const float* __restrict__ bf,
                                             const void* __restrict__ fc2w,
                                             const void* __restrict__ fc2b,
                                             void* __restrict__ out,
                                             const int* __restrict__ flag) {
  __shared__ unsigned hist4[4][256];
  __shared__ unsigned wtot[4];
  __shared__ unsigned selb, selk;
  __shared__ double lg[10];
  __shared__ double mred[2];
  const int tid = threadIdx.x;
  const int row = blockIdx.x;
  const int isb = *flag;
  const int lane = tid & 63;
  const int wv_id = tid >> 6;
  if (tid < 10) lg[tid] = (double)gload(fc2b, tid, isb);
  __syncthreads();

  const int u0 = 2 * tid, u1 = 2 * tid + 1, u2 = 512 + 2 * tid, u3 = 513 + 2 * tid;
  float2 hlo = ((const float2*)(h + row * 1024))[tid];
  float2 hhi = ((const float2*)(h + row * 1024 + 512))[tid];
  float h0 = hlo.x, h1 = hlo.y, h2 = hhi.x, h3 = hhi.y;
  float2 blo = ((const float2*)bf)[tid];
  float2 bhi = ((const float2*)(bf + 512))[tid];
  unsigned k0 = tokey(h0 * blo.x);
  unsigned k1 = tokey(h1 * blo.y);
  unsigned k2 = tokey(h2 * bhi.x);
  unsigned k3 = tokey(h3 * bhi.y);

  unsigned kfix = 0;
  unsigned kk = 100;
  for (int pass = 3; pass >= 0; --pass) {
    const int shift = pass * 8;
    const unsigned himask = (pass == 3) ? 0u : (0xFFFFFFFFu << (shift + 8));
#pragma unroll
    for (int w2 = 0; w2 < 4; ++w2) hist4[w2][tid] = 0;
    __syncthreads();
    unsigned* myh = hist4[wv_id];
    if (((k0 ^ kfix) & himask) == 0) atomicAdd(&myh[(k0 >> shift) & 255u], 1u);
    if (((k1 ^ kfix) & himask) == 0) atomicAdd(&myh[(k1 >> shift) & 255u], 1u);
    if (((k2 ^ kfix) & himask) == 0) atomicAdd(&myh[(k2 >> shift) & 255u], 1u);
    if (((k3 ^ kfix) & himask) == 0) atomicAdd(&myh[(k3 >> shift) & 255u], 1u);
    __syncthreads();
    unsigned own = hist4[0][tid] + hist4[1][tid] + hist4[2][tid] + hist4[3][tid];
    unsigned v = own;
#pragma unroll
    for (int off = 1; off < 64; off <<= 1) {
      unsigned y = __shfl_down(v, off, 64);
      if (lane + off < 64) v += y;
    }
    if (lane == 0) wtot[wv_id] = v;
    __syncthreads();
#pragma unroll
    for (int w2 = 0; w2 < 4; ++w2)
      if (w2 > wv_id) v += wtot[w2];
    unsigned snext = v - own;
    if (v >= kk && snext < kk) {
      selb = (unsigned)tid;
      selk = kk - snext;
    }
    __syncthreads();
    kfix |= selb << shift;
    kk = selk;
    // (5th barrier removed; next pass's zero->sync orders reuse)
  }
  bool kp0 = k0 >= kfix, kp1 = k1 >= kfix, kp2 = k2 >= kfix, kp3 = k3 >= kfix;

  double part[10];
#pragma unroll
  for (int c = 0; c < 10; ++c) part[c] = 0.0;
  if (kp0) {
#pragma unroll
    for (int c = 0; c < 10; ++c) part[c] = fma((double)h0, (double)gload(fc2w, c * 1024 + u0, isb), part[c]);
  }
  if (kp1) {
#pragma unroll
    for (int c = 0; c < 10; ++c) part[c] = fma((double)h1, (double)gload(fc2w, c * 1024 + u1, isb), part[c]);
  }
  if (kp2) {
#pragma unroll
    for (int c = 0; c < 10; ++c) part[c] = fma((double)h2, (double)gload(fc2w, c * 1024 + u2, isb), part[c]);
  }
  if (kp3) {
#pragma unroll
    for (int c = 0; c < 10; ++c) part[c] = fma((double)h3, (double)gload(fc2w, c * 1024 + u3, isb), part[c]);
  }
#pragma unroll
  for (int c = 0; c < 10; ++c) {
    double p = part[c];
    for (int off = 32; off > 0; off >>= 1) p += __shfl_xor(p, off);
    if ((tid & 63) == 0) atomicAdd(&lg[c], p);
  }
  __syncthreads();
  if (tid == 0) {
    double m = lg[0];
#pragma unroll
    for (int c = 1; c < 10; ++c) m = lg[c] > m ? lg[c] : m;
    double sum = 0.0;
#pragma unroll
    for (int c = 0; c < 10; ++c) sum += exp(lg[c] - m);
    mred[0] = m;
    mred[1] = log(sum);
  }
  __syncthreads();
  if (tid < 10) {
    double o = lg[tid] - mred[0] - mred[1];
    if (isb)
      ((unsigned short*)out)[row * 10 + tid] = f2b((float)o);
    else
      ((float*)out)[row * 10 + tid] = (float)o;
  }
}

// ---------------- launch ----------------
extern "C" void kernel_launch(void* const* d_in, const int* in_sizes, int n_in,
                              void* d_out, int out_size, void* d_ws, size_t ws_size,
                              hipStream_t stream) {
  // ws layout (bytes):
  //   WtF   : 9216*1024*4 = 37,748,736  @ 0   (reused as bf[1024] after k_fc1)
  //   wpair : 4096*512*8  = 16,777,216  @ 37,748,736
  //   wcnt  : 4096*4      =     16,384  @ 54,525,952
  //   h     : 4096*1024*4 = 16,777,216  @ 54,542,336
  //   flag  : 4                         @ 71,319,552
  char* ws = (char*)d_ws;
  float* WtF = (float*)ws;
  int2* wpair = (int2*)(ws + 37748736);
  int* wcnt = (int*)(ws + 54525952);
  float* h = (float*)(ws + 54542336);
  int* flag = (int*)(ws + 71319552);
  float* bf = WtF;  // WtF region is dead after k_fc1

  k_detect<<<1, 64, 0, stream>>>(d_in[0], flag);
  k_prep<<<dim3(144, 16), 256, 0, stream>>>(d_in[4], d_in[5], WtF, flag);
  k_conv<<<4096, 256, 0, stream>>>(d_in[0], d_in[1], d_in[2], d_in[3],
                                   wpair, wcnt, flag);
  k_fc1<<<2048 * 8, 128, 0, stream>>>(WtF, wpair, wcnt, d_in[6], h, flag, 0);
  k_fc1<<<2048 * 8, 128, 0, stream>>>(WtF, wpair, wcnt, d_in[6], h, flag, 2048);
  k_boost<<<4, 256, 0, stream>>>(d_in[7], bf, flag);
  k_sel<<<4096, 256, 0, stream>>>(h, bf, d_in[8], d_in[9], d_out, flag);
}

// Round 10
// 584.114 us; speedup vs baseline: 1.2548x; 1.0072x over previous
//
#include <hip/hip_runtime.h>

// ---------------- dtype helpers ----------------
__device__ __forceinline__ float b2f(unsigned short u) {
  return __uint_as_float(((unsigned)u) << 16);
}
__device__ __forceinline__ unsigned short f2b(float f) {
  unsigned u = __float_as_uint(f);
  return (unsigned short)((u + 0x7FFFu + ((u >> 16) & 1u)) >> 16);
}
// load element i of a tensor that is bf16 (isb=1) or fp32 (isb=0)
__device__ __forceinline__ float gload(const void* p, int i, int isb) {
  return isb ? b2f(((const unsigned short*)p)[i]) : ((const float*)p)[i];
}
// monotone bijection float -> uint32 (order-preserving incl. negatives)
__device__ __forceinline__ unsigned tokey(float f) {
  unsigned u = __float_as_uint(f);
  return u ^ (unsigned)(((int)u >> 31) | 0x80000000u);
}

// ---------------- dtype detector (dataset proven fp32; kept for safety) ----------------
__global__ void k_detect(const void* x, int* flag) {
  int tid = threadIdx.x;  // 1 wave
  unsigned short u = ((const unsigned short*)x)[2 * tid];
  int e = (u >> 7) & 0xFF;
  bool sane = (e >= 100 && e <= 140);
  unsigned long long m = __ballot(sane);
  if (tid == 0) *flag = (__popcll(m) >= 40) ? 1 : 0;
}

// ---------------- k_prep: WtF[i][u] = fc1_w[u][i] * (mask<0.5), f32 transposed ----------------
__global__ __launch_bounds__(256) void k_prep(const void* __restrict__ fc1w,
                                              const void* __restrict__ mraw,
                                              float* __restrict__ WtF,
                                              const int* __restrict__ flag) {
  __shared__ float tile[64][65];
  const int isb = *flag;
  const int i0 = blockIdx.x * 64;  // K index (9216)
  const int u0 = blockIdx.y * 64;  // unit index (1024)
  const int tx = threadIdx.x & 63, ty = threadIdx.x >> 6;
  for (int uu = ty; uu < 64; uu += 4) {
    int gi = (u0 + uu) * 9216 + i0 + tx;
    float wv = gload(fc1w, gi, isb);
    float mv = gload(mraw, gi, isb);
    tile[uu][tx] = (mv < 0.5f) ? wv : 0.0f;
  }
  __syncthreads();
  for (int ii = ty; ii < 64; ii += 4)
    WtF[(i0 + ii) * 1024 + u0 + tx] = tile[tx][ii];
}

// ---------------- k_conv: conv5x5 + pool + radix kwinners ----------------
// v10 post-mortem of v9: the (256,4) launch bound clamped VGPR to 64 while the
// conv phase needs ~105 (R[6][16]=96 + w[25] in regs after cw left LDS) ->
// ~26 regs/thread spilled (WRITE_SIZE 12.9->123MB, hbm 896 GB/s of scratch).
// Occupancy gain still netted -5us; v10 keeps the 4-block LDS layout and
// REMOVES the clamp: demand ~105 <= 128 stays under the wave-halving cliff
// (m69: waves halve at VGPR 128), so occupancy remains 4 blocks/CU and the
// spill disappears. Single-variable change vs r9.
//  LDS: pooled 36864 + img/hist union 3136 + cb/bcs 512 + misc 24 = 40536
//  <= 40960 -> 4 blocks/CU.
__global__ __launch_bounds__(256) void k_conv(const void* __restrict__ x,
                                              const void* __restrict__ c1w_g,
                                              const void* __restrict__ c1b_g,
                                              const void* __restrict__ duty_g,
                                              int2* __restrict__ wpair,
                                              int* __restrict__ wcnt,
                                              const int* __restrict__ flag) {
  // img[784] floats (3136B) unioned with hist2[2][256] (2048B): img is dead
  // after the post-conv __syncthreads; hist writes all come after it.
  __shared__ __align__(16) unsigned char u_imghist[3136];
  __shared__ float cb[64], bcs[64];
  __shared__ __align__(16) float pooled[9216];
  __shared__ unsigned wtot[4];
  __shared__ unsigned selb, selk;
  float* img = (float*)u_imghist;
  unsigned* h2a = (unsigned*)u_imghist;           // hist2[0]
  unsigned* h2b = (unsigned*)(u_imghist + 1024);  // hist2[1]
  const int tid = threadIdx.x;
  const int b = blockIdx.x;
  const int isb = *flag;
  const int lane = tid & 63;
  const int wv_id = tid >> 6;

  for (int i = tid; i < 784; i += 256) img[i] = gload(x, b * 784 + i, isb);
  if (tid < 64) {
    cb[tid] = gload(c1b_g, tid, isb);
    float arg = (float)(400.0 / 9216.0) - gload(duty_g, tid, isb);
    bcs[tid] = (float)exp((double)arg);
  }
  __syncthreads();

  // mapping: c = tid>>2 (64), half = tid&1 (2), pg = (tid>>1)&1 (2) -> ph0 = pg*6
  {
    const int c = tid >> 2;
    const int half = tid & 1;
    const int ph0 = ((tid >> 1) & 1) * 6;
    float w[25];
#pragma unroll
    for (int i = 0; i < 25; ++i) w[i] = gload(c1w_g, c * 25 + i, isb);
    const float bias = cb[c];
    float R[6][16];
#pragma unroll
    for (int r = 0; r < 6; ++r) {
      int ir = 2 * ph0 + r;
#pragma unroll
      for (int q = 0; q < 4; ++q)
        ((float4*)&R[r][0])[q] = ((const float4*)img)[ir * 7 + half * 3 + q];
    }
#pragma unroll
    for (int i = 0; i < 6; ++i) {
      const int ph = ph0 + i;
      float a0[12], a1[12];
#pragma unroll
      for (int j = 0; j < 12; ++j) { a0[j] = 0.f; a1[j] = 0.f; }
      // single sequential fmaf chain per conv cell, k = kw*5 + kh order
      // (kh fastest -- Eigen patch linearization) => bit-exact vs reference
#pragma unroll
      for (int kj = 0; kj < 5; ++kj) {       // kw OUTER
#pragma unroll
        for (int kr = 0; kr < 5; ++kr) {     // kh INNER (fastest)
          float wk = w[kr * 5 + kj];
          const float* r0 = &R[(2 * i + kr) % 6][0];
          const float* r1 = &R[(2 * i + kr + 1) % 6][0];
#pragma unroll
          for (int j = 0; j < 12; ++j) {
            a0[j] = fmaf(r0[j + kj], wk, a0[j]);
            a1[j] = fmaf(r1[j + kj], wk, a1[j]);
          }
        }
      }
      int obase = c * 144 + ph * 12 + half * 6;
#pragma unroll
      for (int q = 0; q < 6; ++q) {
        float m = fmaxf(fmaxf(a0[2 * q], a0[2 * q + 1]),
                        fmaxf(a1[2 * q], a1[2 * q + 1]));
        pooled[obase + q] = m + bias;
      }
      if (i < 5) {  // slide: load img rows 2*ph+6, 2*ph+7 over the two oldest
        int ir0 = 2 * ph + 6, ir1 = 2 * ph + 7;
        float* d0 = &R[(2 * i) % 6][0];
        float* d1 = &R[(2 * i + 1) % 6][0];
#pragma unroll
        for (int q = 0; q < 4; ++q) {
          ((float4*)d0)[q] = ((const float4*)img)[ir0 * 7 + half * 3 + q];
          ((float4*)d1)[q] = ((const float4*)img)[ir1 * 7 + half * 3 + q];
        }
      }
    }
  }
  __syncthreads();  // after this barrier img is DEAD -> its LDS becomes hist2

  // compute this thread's 36 select keys ONCE into registers
  unsigned keys[36];
  {
    const float bcf = bcs[tid >> 2];
#pragma unroll
    for (int e4 = 0; e4 < 9; ++e4) {
      float4 pv = ((float4*)pooled)[tid * 9 + e4];
      keys[4 * e4 + 0] = tokey(pv.x * bcf);
      keys[4 * e4 + 1] = tokey(pv.y * bcf);
      keys[4 * e4 + 2] = tokey(pv.z * bcf);
      keys[4 * e4 + 3] = tokey(pv.w * bcf);
    }
  }

  // radix-select the 400th-largest key; 2 split histograms + shfl suffix scan
  unsigned kfix = 0;
  unsigned kk = 400;
  for (int pass = 3; pass >= 0; --pass) {
    const int shift = pass * 8;
    const unsigned himask = (pass == 3) ? 0u : (0xFFFFFFFFu << (shift + 8));
    h2a[tid] = 0;
    h2b[tid] = 0;
    __syncthreads();
    unsigned* myh = (wv_id < 2) ? h2a : h2b;
    if (pass == 3) {
      // run-length aggregated (all-static indices; scalars only)
      unsigned cbin = keys[0] >> 24, ccnt = 1;
#pragma unroll
      for (int e = 1; e < 36; ++e) {
        unsigned bin = keys[e] >> 24;
        if (bin == cbin) {
          ++ccnt;
        } else {
          atomicAdd(&myh[cbin], ccnt);
          cbin = bin;
          ccnt = 1;
        }
      }
      atomicAdd(&myh[cbin], ccnt);
    } else {
#pragma unroll
      for (int e = 0; e < 36; ++e) {
        unsigned key = keys[e];
        if (((key ^ kfix) & himask) == 0)
          atomicAdd(&myh[(key >> shift) & 255u], 1u);
      }
    }
    __syncthreads();
    unsigned own = h2a[tid] + h2b[tid];
    unsigned v = own;
#pragma unroll
    for (int off = 1; off < 64; off <<= 1) {
      unsigned y = __shfl_down(v, off, 64);
      if (lane + off < 64) v += y;
    }
    if (lane == 0) wtot[wv_id] = v;
    __syncthreads();
#pragma unroll
    for (int w2 = 0; w2 < 4; ++w2)
      if (w2 > wv_id) v += wtot[w2];
    unsigned snext = v - own;
    if (v >= kk && snext < kk) {
      selb = (unsigned)tid;
      selk = kk - snext;
    }
    __syncthreads();
    kfix |= selb << shift;
    kk = selk;
    // (5th barrier removed: next pass's zero->sync orders selb/selk reuse)
  }

  // sorted compaction: per-thread count -> shfl prefix scan -> ordered write.
  // keep ALL with key >= kfix (== boosted >= thr bitwise, ties kept like ref)
  unsigned mycnt = 0;
#pragma unroll
  for (int e = 0; e < 36; ++e) mycnt += (keys[e] >= kfix) ? 1u : 0u;
  unsigned px = mycnt;
#pragma unroll
  for (int off = 1; off < 64; off <<= 1) {
    unsigned y = __shfl_up(px, off, 64);
    if (lane >= off) px += y;
  }
  if (lane == 63) wtot[wv_id] = px;
  __syncthreads();
  unsigned base = 0;
#pragma unroll
  for (int w2 = 0; w2 < 4; ++w2)
    if (w2 < wv_id) base += wtot[w2];
  int pos = (int)(base + px - mycnt);  // exclusive prefix
  for (int e = 0; e < 36; ++e) {
    if (keys[e] >= kfix) {
      int o = tid * 36 + e;
      if (pos < 512)
        wpair[b * 512 + pos] = make_int2(__float_as_int(pooled[o]), o << 12);
      ++pos;
    }
  }
  if (tid == 0) {
    unsigned tot = wtot[0] + wtot[1] + wtot[2] + wtot[3];
    wcnt[b] = (int)(tot < 512u ? tot : 512u);
  }
}

// ---------------- k_fc1: XCD-sliced sparse fc1 gather (r3-proven form) ----------------
// Structure optimum per three convergent experiments: scalar s_load (+10us,
// r2), float2 2-unit lanes (+55us/dispatch, r7 -- halved thread count halved
// MLP). Keep: max threads, 1 unit/lane, LDS-staged winner list, 8-pair int4
// unroll. Ascending-w single f32 fmaf chain per unit => bit-identical h.
__global__ __launch_bounds__(128) void k_fc1(const float* __restrict__ WtF,
                                             const int2* __restrict__ wpair,
                                             const int* __restrict__ wcnt,
                                             const void* __restrict__ fc1b,
                                             float* __restrict__ h,
                                             const int* __restrict__ flag,
                                             int img_base) {
  __shared__ __align__(16) int2 wl[512];
  const int tid = threadIdx.x;  // 0..127
  const int img = img_base + (blockIdx.x >> 3);
  const int slice = blockIdx.x & 7;
  const int isb = *flag;
  const int cnt = wcnt[img];
  const int2* __restrict__ wp = wpair + img * 512;
  for (int i = tid; i < cnt; i += 128) wl[i] = wp[i];
  __syncthreads();
  const int u = (slice << 7) + tid;
  const char* __restrict__ Wb = (const char*)WtF + (unsigned)u * 4u;
  const int4* wl4 = (const int4*)wl;  // 2 pairs per int4, 16B-aligned
  float acc = 0.f;
  int w = 0;
  for (; w + 8 <= cnt; w += 8) {
    const int b4 = w >> 1;
    int4 q0 = wl4[b4 + 0];
    int4 q1 = wl4[b4 + 1];
    int4 q2 = wl4[b4 + 2];
    int4 q3 = wl4[b4 + 3];
    acc = fmaf(__int_as_float(q0.x), *(const float*)(Wb + (unsigned)q0.y), acc);
    acc = fmaf(__int_as_float(q0.z), *(const float*)(Wb + (unsigned)q0.w), acc);
    acc = fmaf(__int_as_float(q1.x), *(const float*)(Wb + (unsigned)q1.y), acc);
    acc = fmaf(__int_as_float(q1.z), *(const float*)(Wb + (unsigned)q1.w), acc);
    acc = fmaf(__int_as_float(q2.x), *(const float*)(Wb + (unsigned)q2.y), acc);
    acc = fmaf(__int_as_float(q2.z), *(const float*)(Wb + (unsigned)q2.w), acc);
    acc = fmaf(__int_as_float(q3.x), *(const float*)(Wb + (unsigned)q3.y), acc);
    acc = fmaf(__int_as_float(q3.z), *(const float*)(Wb + (unsigned)q3.w), acc);
  }
  for (; w < cnt; ++w) {
    int2 p = wl[w];
    acc = fmaf(__int_as_float(p.x), *(const float*)(Wb + (unsigned)p.y), acc);
  }
  h[img * 1024 + u] = acc + gload(fc1b, u, isb);
}

// ---------------- k_boost: fc boost factors computed ONCE ----------------
__global__ __launch_bounds__(256) void k_boost(const void* __restrict__ dutyfc,
                                               float* __restrict__ bf,
                                               const int* __restrict__ flag) {
  const int u = blockIdx.x * 256 + threadIdx.x;
  const int isb = *flag;
  if (u < 1024)
    bf[u] = (float)exp((double)(0.09765625f - gload(dutyfc, u, isb)));
}

// ---------------- k_sel: kwinners(k=100, >=thr) + f64 fc2 + log_softmax ----------------
// (r8-proven: split hists + wave scan + 4-barrier radix)
__global__ __launch_bounds__(256) void k_sel(const float* __restrict__ h,
                                             const float* __restrict__ bf,
                                             const void* __restrict__ fc2w,
                                             const void* __restrict__ fc2b,
                                             void* __restrict__ out,
                                             const int* __restrict__ flag) {
  __shared__ unsigned hist4[4][256];
  __shared__ unsigned wtot[4];
  __shared__ unsigned selb, selk;
  __shared__ double lg[10];
  __shared__ double mred[2];
  const int tid = threadIdx.x;
  const int row = blockIdx.x;
  const int isb = *flag;
  const int lane = tid & 63;
  const int wv_id = tid >> 6;
  if (tid < 10) lg[tid] = (double)gload(fc2b, tid, isb);
  __syncthreads();

  const int u0 = 2 * tid, u1 = 2 * tid + 1, u2 = 512 + 2 * tid, u3 = 513 + 2 * tid;
  float2 hlo = ((const float2*)(h + row * 1024))[tid];
  float2 hhi = ((const float2*)(h + row * 1024 + 512))[tid];
  float h0 = hlo.x, h1 = hlo.y, h2 = hhi.x, h3 = hhi.y;
  float2 blo = ((const float2*)bf)[tid];
  float2 bhi = ((const float2*)(bf + 512))[tid];
  unsigned k0 = tokey(h0 * blo.x);
  unsigned k1 = tokey(h1 * blo.y);
  unsigned k2 = tokey(h2 * bhi.x);
  unsigned k3 = tokey(h3 * bhi.y);

  unsigned kfix = 0;
  unsigned kk = 100;
  for (int pass = 3; pass >= 0; --pass) {
    const int shift = pass * 8;
    const unsigned himask = (pass == 3) ? 0u : (0xFFFFFFFFu << (shift + 8));
#pragma unroll
    for (int w2 = 0; w2 < 4; ++w2) hist4[w2][tid] = 0;
    __syncthreads();
    unsigned* myh = hist4[wv_id];
    if (((k0 ^ kfix) & himask) == 0) atomicAdd(&myh[(k0 >> shift) & 255u], 1u);
    if (((k1 ^ kfix) & himask) == 0) atomicAdd(&myh[(k1 >> shift) & 255u], 1u);
    if (((k2 ^ kfix) & himask) == 0) atomicAdd(&myh[(k2 >> shift) & 255u], 1u);
    if (((k3 ^ kfix) & himask) == 0) atomicAdd(&myh[(k3 >> shift) & 255u], 1u);
    __syncthreads();
    unsigned own = hist4[0][tid] + hist4[1][tid] + hist4[2][tid] + hist4[3][tid];
    unsigned v = own;
#pragma unroll
    for (int off = 1; off < 64; off <<= 1) {
      unsigned y = __shfl_down(v, off, 64);
      if (lane + off < 64) v += y;
    }
    if (lane == 0) wtot[wv_id] = v;
    __syncthreads();
#pragma unroll
    for (int w2 = 0; w2 < 4; ++w2)
      if (w2 > wv_id) v += wtot[w2];
    unsigned snext = v - own;
    if (v >= kk && snext < kk) {
      selb = (unsigned)tid;
      selk = kk - snext;
    }
    __syncthreads();
    kfix |= selb << shift;
    kk = selk;
    // (5th barrier removed; next pass's zero->sync orders reuse)
  }
  bool kp0 = k0 >= kfix, kp1 = k1 >= kfix, kp2 = k2 >= kfix, kp3 = k3 >= kfix;

  double part[10];
#pragma unroll
  for (int c = 0; c < 10; ++c) part[c] = 0.0;
  if (kp0) {
#pragma unroll
    for (int c = 0; c < 10; ++c) part[c] = fma((double)h0, (double)gload(fc2w, c * 1024 + u0, isb), part[c]);
  }
  if (kp1) {
#pragma unroll
    for (int c = 0; c < 10; ++c) part[c] = fma((double)h1, (double)gload(fc2w, c * 1024 + u1, isb), part[c]);
  }
  if (kp2) {
#pragma unroll
    for (int c = 0; c < 10; ++c) part[c] = fma((double)h2, (double)gload(fc2w, c * 1024 + u2, isb), part[c]);
  }
  if (kp3) {
#pragma unroll
    for (int c = 0; c < 10; ++c) part[c] = fma((double)h3, (double)gload(fc2w, c * 1024 + u3, isb), part[c]);
  }
#pragma unroll
  for (int c = 0; c < 10; ++c) {
    double p = part[c];
    for (int off = 32; off > 0; off >>= 1) p += __shfl_xor(p, off);
    if ((tid & 63) == 0) atomicAdd(&lg[c], p);
  }
  __syncthreads();
  if (tid == 0) {
    double m = lg[0];
#pragma unroll
    for (int c = 1; c < 10; ++c) m = lg[c] > m ? lg[c] : m;
    double sum = 0.0;
#pragma unroll
    for (int c = 0; c < 10; ++c) sum += exp(lg[c] - m);
    mred[0] = m;
    mred[1] = log(sum);
  }
  __syncthreads();
  if (tid < 10) {
    double o = lg[tid] - mred[0] - mred[1];
    if (isb)
      ((unsigned short*)out)[row * 10 + tid] = f2b((float)o);
    else
      ((float*)out)[row * 10 + tid] = (float)o;
  }
}

// ---------------- launch ----------------
extern "C" void kernel_launch(void* const* d_in, const int* in_sizes, int n_in,
                              void* d_out, int out_size, void* d_ws, size_t ws_size,
                              hipStream_t stream) {
  // ws layout (bytes):
  //   WtF   : 9216*1024*4 = 37,748,736  @ 0   (reused as bf[1024] after k_fc1)
  //   wpair : 4096*512*8  = 16,777,216  @ 37,748,736
  //   wcnt  : 4096*4      =     16,384  @ 54,525,952
  //   h     : 4096*1024*4 = 16,777,216  @ 54,542,336
  //   flag  : 4                         @ 71,319,552
  char* ws = (char*)d_ws;
  float* WtF = (float*)ws;
  int2* wpair = (int2*)(ws + 37748736);
  int* wcnt = (int*)(ws + 54525952);
  float* h = (float*)(ws + 54542336);
  int* flag = (int*)(ws + 71319552);
  float* bf = WtF;  // WtF region is dead after k_fc1

  k_detect<<<1, 64, 0, stream>>>(d_in[0], flag);
  k_prep<<<dim3(144, 16), 256, 0, stream>>>(d_in[4], d_in[5], WtF, flag);
  k_conv<<<4096, 256, 0, stream>>>(d_in[0], d_in[1], d_in[2], d_in[3],
                                   wpair, wcnt, flag);
  k_fc1<<<2048 * 8, 128, 0, stream>>>(WtF, wpair, wcnt, d_in[6], h, flag, 0);
  k_fc1<<<2048 * 8, 128, 0, stream>>>(WtF, wpair, wcnt, d_in[6], h, flag, 2048);
  k_boost<<<4, 256, 0, stream>>>(d_in[7], bf, flag);
  k_sel<<<4096, 256, 0, stream>>>(h, bf, d_in[8], d_in[9], d_out, flag);
}